// Round 1
// baseline (1183.553 us; speedup 1.0000x reference)
//
#include <hip/hip_runtime.h>

#define DI __device__ __forceinline__
typedef unsigned short u16;
typedef __attribute__((ext_vector_type(8))) short short8;
typedef __attribute__((ext_vector_type(4))) float f32x4;

constexpr int Bz = 2, Tz = 2048, Ez = 2048, Hz = 16, Dz = 64;
constexpr int M_ROWS = Bz * Tz;  // 4096
constexpr float LAMBDA_INIT = 0.7836057665316245f;   // 0.8 - 0.6*exp(-3.6)
constexpr float ONE_MINUS_LI = 1.0f - 0.7836057665316245f;

DI u16 f2bf(float f) {
  unsigned u = __builtin_bit_cast(unsigned, f);
  u = (u + 0x7fffu + ((u >> 16) & 1u)) >> 16;  // RNE
  return (u16)u;
}

DI void gload_lds16(const void* g, void* l) {
  __builtin_amdgcn_global_load_lds((const __attribute__((address_space(1))) void*)g,
                                   (__attribute__((address_space(3))) void*)l, 16, 0, 0);
}

// ---------------- cast fp32 -> bf16 (vectorized) ----------------
__global__ void cast_bf16_kernel(const float* __restrict__ in, u16* __restrict__ out, int n4) {
  int i = blockIdx.x * blockDim.x + threadIdx.x;
  if (i >= n4) return;
  float4 v = reinterpret_cast<const float4*>(in)[i];
  ushort4 o;
  o.x = f2bf(v.x); o.y = f2bf(v.y); o.z = f2bf(v.z); o.w = f2bf(v.w);
  reinterpret_cast<ushort4*>(out)[i] = o;
}

// ---------------- GEMM: C[M,N] = A[M,K] * B[N,K]^T, bf16 in, fp32 out ----------------
// 128x128 tile, BK=64, 4 waves (2x2 of 64x64), 16x16x32 bf16 MFMA.
__global__ __launch_bounds__(256, 2)
void gemm_bt(const u16* __restrict__ A, const u16* __restrict__ Bm,
             float* __restrict__ C, int M, int N, int K) {
  __shared__ u16 As[128 * 64];
  __shared__ u16 Bs[128 * 64];
  const int tid = threadIdx.x;
  const int lane = tid & 63;
  const int lq = lane & 15, lg = lane >> 4;
  const int w = tid >> 6;
  const int wm = (w >> 1) * 64, wn = (w & 1) * 64;
  const int m0 = blockIdx.x * 128, n0 = blockIdx.y * 128;

  f32x4 acc[4][4] = {};

  const u16* Ag = A + (size_t)(m0 + (tid >> 3)) * K + (tid & 7) * 8;
  const u16* Bg = Bm + (size_t)(n0 + (tid >> 3)) * K + (tid & 7) * 8;

  for (int kt = 0; kt < K; kt += 64) {
    __syncthreads();
#pragma unroll
    for (int ch = 0; ch < 4; ++ch) {
      gload_lds16(Ag + (size_t)ch * 32 * K + kt, &As[(ch * 256 + tid) * 8]);
      gload_lds16(Bg + (size_t)ch * 32 * K + kt, &Bs[(ch * 256 + tid) * 8]);
    }
    __syncthreads();
#pragma unroll
    for (int ks = 0; ks < 2; ++ks) {
      short8 af[4], bfr[4];
#pragma unroll
      for (int i = 0; i < 4; ++i)
        af[i] = *reinterpret_cast<const short8*>(&As[(wm + i * 16 + lq) * 64 + ks * 32 + lg * 8]);
#pragma unroll
      for (int j = 0; j < 4; ++j)
        bfr[j] = *reinterpret_cast<const short8*>(&Bs[(wn + j * 16 + lq) * 64 + ks * 32 + lg * 8]);
#pragma unroll
      for (int i = 0; i < 4; ++i)
#pragma unroll
        for (int j = 0; j < 4; ++j)
          acc[i][j] = __builtin_amdgcn_mfma_f32_16x16x32_bf16(af[i], bfr[j], acc[i][j], 0, 0, 0);
    }
  }
#pragma unroll
  for (int i = 0; i < 4; ++i)
#pragma unroll
    for (int j = 0; j < 4; ++j)
#pragma unroll
      for (int r = 0; r < 4; ++r)
        C[(size_t)(m0 + wm + i * 16 + lg * 4 + r) * N + (n0 + wn + j * 16 + lq)] = acc[i][j][r];
}

// ---------------- RoPE (interleaved) + pack q,k to bf16 [b][c][h][t][d] ----------------
__global__ void rope_pack_kernel(const float* __restrict__ qf, const float* __restrict__ kf,
                                 const float* __restrict__ cosb, const float* __restrict__ sinb,
                                 u16* __restrict__ Qb, u16* __restrict__ Kb) {
  int idx = blockIdx.x * blockDim.x + threadIdx.x;  // (b*T + t)*2H + hh
  if (idx >= Bz * Tz * 2 * Hz) return;
  const int hh = idx & (2 * Hz - 1);
  const int t = (idx >> 5) & (Tz - 1);
  const int b = idx >> 16;
  const int c = hh & 1, h = hh >> 1;
  const float* cr = cosb + t * 32;
  const float* sr = sinb + t * 32;
  const float* qrow = qf + (size_t)idx * 64;
  const float* krow = kf + (size_t)idx * 64;
  u16* qo = Qb + ((((size_t)b * 2 + c) * Hz + h) * Tz + t) * 64;
  u16* ko = Kb + ((((size_t)b * 2 + c) * Hz + h) * Tz + t) * 64;
#pragma unroll 8
  for (int i = 0; i < 32; ++i) {
    const float cv = cr[i], sv = sr[i];
    const float q1 = qrow[2 * i], q2 = qrow[2 * i + 1];
    qo[2 * i]     = f2bf(q1 * cv - q2 * sv);
    qo[2 * i + 1] = f2bf(q1 * sv + q2 * cv);
    const float k1 = krow[2 * i], k2 = krow[2 * i + 1];
    ko[2 * i]     = f2bf(k1 * cv - k2 * sv);
    ko[2 * i + 1] = f2bf(k1 * sv + k2 * cv);
  }
}

// ---------------- V transpose+cast: vf (b,t,h,128) fp32 -> Vt [b][h][n][t] bf16 ----------------
__global__ void v_pack_kernel(const float* __restrict__ vf, u16* __restrict__ Vt) {
  int idx = blockIdx.x * blockDim.x + threadIdx.x;  // (b*H + h)*T + t, t fastest
  if (idx >= Bz * Hz * Tz) return;
  const int t = idx & (Tz - 1);
  const int h = (idx >> 11) & (Hz - 1);
  const int b = idx >> 15;
  const float* vrow = vf + ((size_t)(b * Tz + t)) * 2048 + h * 128;
  u16* vo = Vt + (((size_t)b * Hz + h) * 128) * Tz + t;
#pragma unroll 8
  for (int n = 0; n < 128; ++n)
    vo[(size_t)n * Tz] = f2bf(vrow[n]);
}

// ---------------- differential flash attention + RMS-norm epilogue ----------------
// grid (T/64, H, B); 4 waves, 16 q-rows each; KV steps of 32; both comps share V.
__global__ __launch_bounds__(256, 2)
void attn_kernel(const u16* __restrict__ Qb, const u16* __restrict__ Kb,
                 const u16* __restrict__ Vt,
                 const float* __restrict__ lq1, const float* __restrict__ lk1,
                 const float* __restrict__ lq2, const float* __restrict__ lk2,
                 const float* __restrict__ g, u16* __restrict__ Ao) {
  __shared__ u16 Plds[4][16 * 32];
  const int tid = threadIdx.x;
  const int lane = tid & 63;
  const int lq = lane & 15, lg = lane >> 4;
  const int w = tid >> 6;
  const int h = blockIdx.y, b = blockIdx.z;
  const int q0 = blockIdx.x * 64 + w * 16;

  float s1 = 0.f, s2 = 0.f;
  for (int i = 0; i < 64; ++i) { s1 += lq1[i] * lk1[i]; s2 += lq2[i] * lk2[i]; }
  const float lambda_full = __expf(s1) - __expf(s2) + LAMBDA_INIT;

  const u16* Qp[2]; const u16* Kp[2];
#pragma unroll
  for (int c = 0; c < 2; ++c) {
    Qp[c] = Qb + ((((size_t)b * 2 + c) * Hz + h) * Tz) * 64;
    Kp[c] = Kb + ((((size_t)b * 2 + c) * Hz + h) * Tz) * 64;
  }
  const u16* Vp = Vt + (((size_t)b * Hz + h) * 128) * Tz;

  short8 qfr[2][2];
#pragma unroll
  for (int c = 0; c < 2; ++c)
#pragma unroll
    for (int ks = 0; ks < 2; ++ks)
      qfr[c][ks] = *reinterpret_cast<const short8*>(&Qp[c][(size_t)(q0 + lq) * 64 + ks * 32 + lg * 8]);

  f32x4 O[2][8] = {};
  float mst[2][4], lst[2][4];
#pragma unroll
  for (int c = 0; c < 2; ++c)
#pragma unroll
    for (int r = 0; r < 4; ++r) { mst[c][r] = -3.0e38f; lst[c][r] = 0.f; }

  const int ktmax = (q0 + 15) >> 5;
  for (int kt = 0; kt <= ktmax; ++kt) {
    const int kv0 = kt * 32;
    const bool full = (kv0 + 31) <= q0;
#pragma unroll
    for (int c = 0; c < 2; ++c) {
      f32x4 s[2];
#pragma unroll
      for (int t2 = 0; t2 < 2; ++t2) {
        f32x4 a = {0.f, 0.f, 0.f, 0.f};
#pragma unroll
        for (int ks = 0; ks < 2; ++ks) {
          short8 kfr = *reinterpret_cast<const short8*>(
              &Kp[c][(size_t)(kv0 + t2 * 16 + lq) * 64 + ks * 32 + lg * 8]);
          a = __builtin_amdgcn_mfma_f32_16x16x32_bf16(qfr[c][ks], kfr, a, 0, 0, 0);
        }
        s[t2] = a;
      }
#pragma unroll
      for (int t2 = 0; t2 < 2; ++t2)
#pragma unroll
        for (int r = 0; r < 4; ++r) {
          float v = s[t2][r] * 0.125f;
          if (!full) {
            const int row = q0 + lg * 4 + r;
            const int col = kv0 + t2 * 16 + lq;
            if (col > row) v = -3.0e38f;
          }
          s[t2][r] = v;
        }
      float alr[4];
#pragma unroll
      for (int r = 0; r < 4; ++r) {
        float mx = fmaxf(s[0][r], s[1][r]);
        mx = fmaxf(mx, __shfl_xor(mx, 1));
        mx = fmaxf(mx, __shfl_xor(mx, 2));
        mx = fmaxf(mx, __shfl_xor(mx, 4));
        mx = fmaxf(mx, __shfl_xor(mx, 8));
        const float mnew = fmaxf(mst[c][r], mx);
        const float p0 = __expf(s[0][r] - mnew);
        const float p1 = __expf(s[1][r] - mnew);
        s[0][r] = p0; s[1][r] = p1;
        float ps = p0 + p1;
        ps += __shfl_xor(ps, 1);
        ps += __shfl_xor(ps, 2);
        ps += __shfl_xor(ps, 4);
        ps += __shfl_xor(ps, 8);
        const float alpha = __expf(mst[c][r] - mnew);
        lst[c][r] = lst[c][r] * alpha + ps;
        mst[c][r] = mnew;
        alr[r] = alpha;
      }
#pragma unroll
      for (int jn = 0; jn < 8; ++jn)
#pragma unroll
        for (int r = 0; r < 4; ++r)
          O[c][jn][r] *= alr[r];
      // P (C-layout) -> LDS -> A-fragment layout
      u16* pl = &Plds[w][0];
#pragma unroll
      for (int t2 = 0; t2 < 2; ++t2)
#pragma unroll
        for (int r = 0; r < 4; ++r)
          pl[(lg * 4 + r) * 32 + t2 * 16 + lq] = f2bf(s[t2][r]);
      asm volatile("s_waitcnt lgkmcnt(0)" ::: "memory");
      __builtin_amdgcn_sched_barrier(0);
      const short8 pf = *reinterpret_cast<const short8*>(&pl[lq * 32 + lg * 8]);
#pragma unroll
      for (int jn = 0; jn < 8; ++jn) {
        const short8 vfr = *reinterpret_cast<const short8*>(
            &Vp[(size_t)(jn * 16 + lq) * Tz + kv0 + lg * 8]);
        O[c][jn] = __builtin_amdgcn_mfma_f32_16x16x32_bf16(pf, vfr, O[c][jn], 0, 0, 0);
      }
    }
  }

  // epilogue: combine, RMS-norm over 128, * g * (1 - lambda_init), write bf16
  float gv[8];
#pragma unroll
  for (int jn = 0; jn < 8; ++jn) gv[jn] = g[jn * 16 + lq];
#pragma unroll
  for (int r = 0; r < 4; ++r) {
    const float inv1 = 1.f / lst[0][r];
    const float inv2 = 1.f / lst[1][r];
    float av[8];
    float ss = 0.f;
#pragma unroll
    for (int jn = 0; jn < 8; ++jn) {
      const float a = O[0][jn][r] * inv1 - lambda_full * (O[1][jn][r] * inv2);
      av[jn] = a;
      ss += a * a;
    }
    ss += __shfl_xor(ss, 1);
    ss += __shfl_xor(ss, 2);
    ss += __shfl_xor(ss, 4);
    ss += __shfl_xor(ss, 8);
    const float sc = rsqrtf(ss * (1.f / 128.f) + 1e-5f) * ONE_MINUS_LI;
    const int row = q0 + lg * 4 + r;
    u16* orow = Ao + ((size_t)b * Tz + row) * 2048 + h * 128;
#pragma unroll
    for (int jn = 0; jn < 8; ++jn)
      orow[jn * 16 + lq] = f2bf(av[jn] * sc * gv[jn]);
  }
}

extern "C" void kernel_launch(void* const* d_in, const int* in_sizes, int n_in,
                              void* d_out, int out_size, void* d_ws, size_t ws_size,
                              hipStream_t stream) {
  const float* x    = (const float*)d_in[0];
  const float* cosb = (const float*)d_in[1];
  const float* sinb = (const float*)d_in[2];
  const float* Wq   = (const float*)d_in[3];
  const float* Wk   = (const float*)d_in[4];
  const float* Wv   = (const float*)d_in[5];
  const float* Wo   = (const float*)d_in[6];
  const float* lq1  = (const float*)d_in[7];
  const float* lk1  = (const float*)d_in[8];
  const float* lq2  = (const float*)d_in[9];
  const float* lk2  = (const float*)d_in[10];
  const float* g    = (const float*)d_in[11];
  float* out = (float*)d_out;

  char* ws = (char*)d_ws;
  size_t off = 0;
  auto alloc = [&](size_t bytes) -> void* {
    void* p = ws + off;
    off += (bytes + 255) & ~(size_t)255;
    return p;
  };
  u16* xb   = (u16*)alloc((size_t)M_ROWS * Ez * 2);
  u16* Wqb  = (u16*)alloc((size_t)Ez * Ez * 2);
  u16* Wkb  = (u16*)alloc((size_t)Ez * Ez * 2);
  u16* Wvb  = (u16*)alloc((size_t)Ez * Ez * 2);
  u16* Wob  = (u16*)alloc((size_t)Ez * Ez * 2);
  float* qf = (float*)alloc((size_t)M_ROWS * Ez * 4);
  float* kf = (float*)alloc((size_t)M_ROWS * Ez * 4);
  float* vf = (float*)alloc((size_t)M_ROWS * Ez * 4);
  u16* Qb   = (u16*)alloc((size_t)Bz * 2 * Hz * Tz * Dz * 2);
  u16* Kb   = (u16*)alloc((size_t)Bz * 2 * Hz * Tz * Dz * 2);
  u16* Vt   = (u16*)alloc((size_t)Bz * Hz * 128 * Tz * 2);
  u16* Ab   = (u16*)alloc((size_t)M_ROWS * Ez * 2);

  const int n4x = M_ROWS * Ez / 4;
  cast_bf16_kernel<<<dim3(n4x / 256), 256, 0, stream>>>(x, xb, n4x);
  const int n4w = Ez * Ez / 4;
  cast_bf16_kernel<<<dim3(n4w / 256), 256, 0, stream>>>(Wq, Wqb, n4w);
  cast_bf16_kernel<<<dim3(n4w / 256), 256, 0, stream>>>(Wk, Wkb, n4w);
  cast_bf16_kernel<<<dim3(n4w / 256), 256, 0, stream>>>(Wv, Wvb, n4w);
  cast_bf16_kernel<<<dim3(n4w / 256), 256, 0, stream>>>(Wo, Wob, n4w);

  dim3 gg(M_ROWS / 128, Ez / 128);
  gemm_bt<<<gg, 256, 0, stream>>>(xb, Wqb, qf, M_ROWS, Ez, Ez);
  gemm_bt<<<gg, 256, 0, stream>>>(xb, Wkb, kf, M_ROWS, Ez, Ez);
  gemm_bt<<<gg, 256, 0, stream>>>(xb, Wvb, vf, M_ROWS, Ez, Ez);

  rope_pack_kernel<<<dim3(Bz * Tz * 2 * Hz / 256), 256, 0, stream>>>(qf, kf, cosb, sinb, Qb, Kb);
  v_pack_kernel<<<dim3(Bz * Hz * Tz / 256), 256, 0, stream>>>(vf, Vt);

  attn_kernel<<<dim3(Tz / 64, Hz, Bz), 256, 0, stream>>>(Qb, Kb, Vt, lq1, lk1, lq2, lk2, g, Ab);

  gemm_bt<<<gg, 256, 0, stream>>>(Ab, Wob, out, M_ROWS, Ez, Ez);
}

// Round 3
// 640.348 us; speedup vs baseline: 1.8483x; 1.8483x over previous
//
#include <hip/hip_runtime.h>

#define DI __device__ __forceinline__
typedef unsigned short u16;
typedef __attribute__((ext_vector_type(8))) short short8;
typedef __attribute__((ext_vector_type(4))) float f32x4;

constexpr int Bz = 2, Tz = 2048, Ez = 2048, Hz = 16, Dz = 64;
constexpr int M_ROWS = Bz * Tz;  // 4096
constexpr float LAMBDA_INIT = 0.7836057665316245f;   // 0.8 - 0.6*exp(-3.6)
constexpr float ONE_MINUS_LI = 1.0f - LAMBDA_INIT;

DI u16 f2bf(float f) {
  unsigned u = __builtin_bit_cast(unsigned, f);
  u = (u + 0x7fffu + ((u >> 16) & 1u)) >> 16;  // RNE
  return (u16)u;
}

DI void gload_lds16(const void* g, void* l) {
  __builtin_amdgcn_global_load_lds((const __attribute__((address_space(1))) void*)g,
                                   (__attribute__((address_space(3))) void*)l, 16, 0, 0);
}

// ---------------- cast fp32 -> bf16 (vectorized) ----------------
__global__ void cast_bf16_kernel(const float* __restrict__ in, u16* __restrict__ out, int n4) {
  int i = blockIdx.x * blockDim.x + threadIdx.x;
  if (i >= n4) return;
  float4 v = reinterpret_cast<const float4*>(in)[i];
  ushort4 o;
  o.x = f2bf(v.x); o.y = f2bf(v.y); o.z = f2bf(v.z); o.w = f2bf(v.w);
  reinterpret_cast<ushort4*>(out)[i] = o;
}

// ---------------- GEMM: C[M,N] = A[M,K] * B[N,K]^T, bf16 in, fp32 out ----------------
__global__ __launch_bounds__(256, 2)
void gemm_bt(const u16* __restrict__ A, const u16* __restrict__ Bm,
             float* __restrict__ C, int M, int N, int K) {
  __shared__ u16 As[128 * 64];
  __shared__ u16 Bs[128 * 64];
  const int tid = threadIdx.x;
  const int lane = tid & 63;
  const int lq = lane & 15, lg = lane >> 4;
  const int w = tid >> 6;
  const int wm = (w >> 1) * 64, wn = (w & 1) * 64;
  const int m0 = blockIdx.x * 128, n0 = blockIdx.y * 128;

  f32x4 acc[4][4] = {};

  const u16* Ag = A + (size_t)(m0 + (tid >> 3)) * K + (tid & 7) * 8;
  const u16* Bg = Bm + (size_t)(n0 + (tid >> 3)) * K + (tid & 7) * 8;

  for (int kt = 0; kt < K; kt += 64) {
    __syncthreads();
#pragma unroll
    for (int ch = 0; ch < 4; ++ch) {
      gload_lds16(Ag + (size_t)ch * 32 * K + kt, &As[(ch * 256 + tid) * 8]);
      gload_lds16(Bg + (size_t)ch * 32 * K + kt, &Bs[(ch * 256 + tid) * 8]);
    }
    __syncthreads();
#pragma unroll
    for (int ks = 0; ks < 2; ++ks) {
      short8 af[4], bfr[4];
#pragma unroll
      for (int i = 0; i < 4; ++i)
        af[i] = *reinterpret_cast<const short8*>(&As[(wm + i * 16 + lq) * 64 + ks * 32 + lg * 8]);
#pragma unroll
      for (int j = 0; j < 4; ++j)
        bfr[j] = *reinterpret_cast<const short8*>(&Bs[(wn + j * 16 + lq) * 64 + ks * 32 + lg * 8]);
#pragma unroll
      for (int i = 0; i < 4; ++i)
#pragma unroll
        for (int j = 0; j < 4; ++j)
          acc[i][j] = __builtin_amdgcn_mfma_f32_16x16x32_bf16(af[i], bfr[j], acc[i][j], 0, 0, 0);
    }
  }
#pragma unroll
  for (int i = 0; i < 4; ++i)
#pragma unroll
    for (int j = 0; j < 4; ++j)
#pragma unroll
      for (int r = 0; r < 4; ++r)
        C[(size_t)(m0 + wm + i * 16 + lg * 4 + r) * N + (n0 + wn + j * 16 + lq)] = acc[i][j][r];
}

// ---------------- RoPE (interleaved) + pack q,k to bf16 [b][c][h][t][d]; q scaled by 0.125 ----------------
__global__ void rope_pack_kernel(const float* __restrict__ qf, const float* __restrict__ kf,
                                 const float* __restrict__ cosb, const float* __restrict__ sinb,
                                 u16* __restrict__ Qb, u16* __restrict__ Kb) {
  int idx = blockIdx.x * blockDim.x + threadIdx.x;  // (b*T + t)*2H + hh
  if (idx >= Bz * Tz * 2 * Hz) return;
  const int hh = idx & (2 * Hz - 1);
  const int t = (idx >> 5) & (Tz - 1);
  const int b = idx >> 16;
  const int c = hh & 1, h = hh >> 1;
  const float* cr = cosb + t * 32;
  const float* sr = sinb + t * 32;
  const float* qrow = qf + (size_t)idx * 64;
  const float* krow = kf + (size_t)idx * 64;
  u16* qo = Qb + ((((size_t)b * 2 + c) * Hz + h) * Tz + t) * 64;
  u16* ko = Kb + ((((size_t)b * 2 + c) * Hz + h) * Tz + t) * 64;
#pragma unroll 8
  for (int i = 0; i < 32; ++i) {
    const float cv = cr[i], sv = sr[i];
    const float q1 = qrow[2 * i], q2 = qrow[2 * i + 1];
    qo[2 * i]     = f2bf((q1 * cv - q2 * sv) * 0.125f);
    qo[2 * i + 1] = f2bf((q1 * sv + q2 * cv) * 0.125f);
    const float k1 = krow[2 * i], k2 = krow[2 * i + 1];
    ko[2 * i]     = f2bf(k1 * cv - k2 * sv);
    ko[2 * i + 1] = f2bf(k1 * sv + k2 * cv);
  }
}

// ---------------- V transpose+cast: vf (b,t,h,128) fp32 -> Vt [b][h][n][t] bf16 ----------------
__global__ void v_pack_kernel(const float* __restrict__ vf, u16* __restrict__ Vt) {
  int idx = blockIdx.x * blockDim.x + threadIdx.x;
  if (idx >= Bz * Hz * Tz) return;
  const int t = idx & (Tz - 1);
  const int h = (idx >> 11) & (Hz - 1);
  const int b = idx >> 15;
  const float* vrow = vf + ((size_t)(b * Tz + t)) * 2048 + h * 128;
  u16* vo = Vt + (((size_t)b * Hz + h) * 128) * Tz + t;
#pragma unroll 8
  for (int n = 0; n < 128; ++n)
    vo[(size_t)n * Tz] = f2bf(vrow[n]);
}

// ---------------- differential flash attention + RMS-norm epilogue ----------------
// 8 waves x 16 q-rows = 128-row q-tile; KVBLK=64; LDS-staged K/V (double-buffered,
// XOR-swizzled via pre-swizzled global source); paired q-tiles (qt, 15-qt) for balance.
__global__ __launch_bounds__(512, 2)
void attn_kernel(const u16* __restrict__ Qb, const u16* __restrict__ Kb,
                 const u16* __restrict__ Vt,
                 const float* __restrict__ lq1, const float* __restrict__ lk1,
                 const float* __restrict__ lq2, const float* __restrict__ lk2,
                 const float* __restrict__ g, u16* __restrict__ Ao) {
  __shared__ __align__(16) u16 Ks[2][2][64 * 64];    // [buf][comp][row*64+d]  32 KB
  __shared__ __align__(16) u16 Vs[2][128 * 64];      // [buf][n*64+kv]         32 KB
  __shared__ __align__(16) u16 Plds[8][2][16 * 64];  // per-wave P staging     32 KB

  const int tid = threadIdx.x;
  const int l = tid & 63;
  const int lq = l & 15, lg = l >> 4;
  const int w = tid >> 6;
  const int h = blockIdx.y, b = blockIdx.z;

  // lambda_full via wave-reduce (D=64 == wave size)
  float v1 = lq1[l] * lk1[l], v2 = lq2[l] * lk2[l];
#pragma unroll
  for (int off = 1; off < 64; off <<= 1) {
    v1 += __shfl_xor(v1, off);
    v2 += __shfl_xor(v2, off);
  }
  const float lambda_full = __expf(v1) - __expf(v2) + LAMBDA_INIT;

  const u16* Qp[2];
  const u16* Kp[2];
#pragma unroll
  for (int c = 0; c < 2; ++c) {
    Qp[c] = Qb + ((((size_t)b * 2 + c) * Hz + h) * Tz) * 64;
    Kp[c] = Kb + ((((size_t)b * 2 + c) * Hz + h) * Tz) * 64;
  }
  const u16* Vp = Vt + (((size_t)b * Hz + h) * 128) * (size_t)Tz;

  float gv[8];
#pragma unroll
  for (int jn = 0; jn < 8; ++jn) gv[jn] = g[jn * 16 + lq];

  const int krow = tid >> 3;
  const int kcl = ((tid & 7) ^ (krow & 7)) << 3;  // pre-swizzled source col (elements)

  for (int seg = 0; seg < 2; ++seg) {
    const int qt = seg ? (15 - (int)blockIdx.x) : (int)blockIdx.x;
    const int q0 = qt << 7;
    const int q0w = q0 + w * 16;
    const int ktmax = (q0 + 127) >> 6;  // 2*qt+1

    short8 qfr[2][2];
#pragma unroll
    for (int c = 0; c < 2; ++c)
#pragma unroll
      for (int ks = 0; ks < 2; ++ks)
        qfr[c][ks] = *reinterpret_cast<const short8*>(
            &Qp[c][(size_t)(q0w + lq) * 64 + ks * 32 + lg * 8]);

    f32x4 O[2][8] = {};
    float mst[2][4], lst[2][4];
#pragma unroll
    for (int c = 0; c < 2; ++c)
#pragma unroll
      for (int r = 0; r < 4; ++r) { mst[c][r] = -3.0e38f; lst[c][r] = 0.f; }

    auto STAGE = [&](int bf, int kt) {
      const int kv0 = kt << 6;
#pragma unroll
      for (int c = 0; c < 2; ++c)
        gload_lds16(Kp[c] + (size_t)(kv0 + krow) * 64 + kcl, &Ks[bf][c][tid * 8]);
#pragma unroll
      for (int p = 0; p < 2; ++p) {
        const int idx = tid + p * 512;
        const int vr = idx >> 3;
        const int vc = ((idx & 7) ^ (vr & 7)) << 3;
        gload_lds16(Vp + (size_t)vr * Tz + kv0 + vc, &Vs[bf][idx * 8]);
      }
    };

    STAGE(0, 0);
    __syncthreads();
    int buf = 0;
    for (int kt = 0; kt <= ktmax; ++kt) {
      if (kt < ktmax) STAGE(buf ^ 1, kt + 1);
      const int kv0 = kt << 6;
      if (kv0 <= q0w + 15) {  // wave-uniform causal skip
        const bool notfull = (kv0 + 63) > q0w;
#pragma unroll
        for (int c = 0; c < 2; ++c) {
          f32x4 s[4];
#pragma unroll
          for (int t2 = 0; t2 < 4; ++t2) {
            f32x4 a = {0.f, 0.f, 0.f, 0.f};
#pragma unroll
            for (int ks = 0; ks < 2; ++ks) {
              const int row = t2 * 16 + lq;
              const short8 kfr = *reinterpret_cast<const short8*>(
                  &Ks[buf][c][row * 64 + ((((ks << 2) + lg) ^ (row & 7)) << 3)]);
              a = __builtin_amdgcn_mfma_f32_16x16x32_bf16(qfr[c][ks], kfr, a, 0, 0, 0);
            }
            s[t2] = a;
          }
          if (notfull) {
#pragma unroll
            for (int t2 = 0; t2 < 4; ++t2)
#pragma unroll
              for (int r = 0; r < 4; ++r)
                if (kv0 + t2 * 16 + lq > q0w + lg * 4 + r) s[t2][r] = -3.0e38f;
          }
          float alr[4];
#pragma unroll
          for (int r = 0; r < 4; ++r) {
            float mx = fmaxf(fmaxf(s[0][r], s[1][r]), fmaxf(s[2][r], s[3][r]));
            mx = fmaxf(mx, __shfl_xor(mx, 1));
            mx = fmaxf(mx, __shfl_xor(mx, 2));
            mx = fmaxf(mx, __shfl_xor(mx, 4));
            mx = fmaxf(mx, __shfl_xor(mx, 8));
            const float mnew = fmaxf(mst[c][r], mx);
            float ps = 0.f;
#pragma unroll
            for (int t2 = 0; t2 < 4; ++t2) {
              const float p = __expf(s[t2][r] - mnew);
              s[t2][r] = p;
              ps += p;
            }
            ps += __shfl_xor(ps, 1);
            ps += __shfl_xor(ps, 2);
            ps += __shfl_xor(ps, 4);
            ps += __shfl_xor(ps, 8);
            const float alpha = __expf(mst[c][r] - mnew);
            lst[c][r] = lst[c][r] * alpha + ps;
            mst[c][r] = mnew;
            alr[r] = alpha;
          }
#pragma unroll
          for (int jn = 0; jn < 8; ++jn)
#pragma unroll
            for (int r = 0; r < 4; ++r)
              O[c][jn][r] *= alr[r];
          u16* pl = &Plds[w][c][0];
#pragma unroll
          for (int t2 = 0; t2 < 4; ++t2)
#pragma unroll
            for (int r = 0; r < 4; ++r) {
              const int prow = lg * 4 + r, pcol = t2 * 16 + lq;
              pl[prow * 64 + (((pcol >> 3) ^ (prow & 7)) << 3) + (pcol & 7)] = f2bf(s[t2][r]);
            }
        }
        asm volatile("s_waitcnt lgkmcnt(0)" ::: "memory");
        __builtin_amdgcn_sched_barrier(0);
        short8 pf[2][2];
#pragma unroll
        for (int c = 0; c < 2; ++c)
#pragma unroll
          for (int kseg = 0; kseg < 2; ++kseg)
            pf[c][kseg] = *reinterpret_cast<const short8*>(
                &Plds[w][c][lq * 64 + ((((kseg << 2) + lg) ^ (lq & 7)) << 3)]);
#pragma unroll
        for (int jn = 0; jn < 8; ++jn)
#pragma unroll
          for (int kseg = 0; kseg < 2; ++kseg) {
            const int vr = jn * 16 + lq;
            const short8 vfr = *reinterpret_cast<const short8*>(
                &Vs[buf][vr * 64 + ((((kseg << 2) + lg) ^ (vr & 7)) << 3)]);
            O[0][jn] = __builtin_amdgcn_mfma_f32_16x16x32_bf16(pf[0][kseg], vfr, O[0][jn], 0, 0, 0);
            O[1][jn] = __builtin_amdgcn_mfma_f32_16x16x32_bf16(pf[1][kseg], vfr, O[1][jn], 0, 0, 0);
          }
      }
      __syncthreads();
      buf ^= 1;
    }

    // epilogue: combine, RMS-norm over 128, * g * (1 - lambda_init), write bf16
#pragma unroll
    for (int r = 0; r < 4; ++r) {
      const float inv1 = 1.f / lst[0][r];
      const float inv2 = 1.f / lst[1][r];
      float av[8];
      float ss = 0.f;
#pragma unroll
      for (int jn = 0; jn < 8; ++jn) {
        const float a2 = O[0][jn][r] * inv1 - lambda_full * (O[1][jn][r] * inv2);
        av[jn] = a2;
        ss += a2 * a2;
      }
      ss += __shfl_xor(ss, 1);
      ss += __shfl_xor(ss, 2);
      ss += __shfl_xor(ss, 4);
      ss += __shfl_xor(ss, 8);
      const float sc = rsqrtf(ss * (1.f / 128.f) + 1e-5f) * ONE_MINUS_LI;
      const int row = q0w + lg * 4 + r;
      u16* orow = Ao + ((size_t)b * Tz + row) * 2048 + h * 128;
#pragma unroll
      for (int jn = 0; jn < 8; ++jn)
        orow[jn * 16 + lq] = f2bf(av[jn] * sc * gv[jn]);
    }
  }
}

extern "C" void kernel_launch(void* const* d_in, const int* in_sizes, int n_in,
                              void* d_out, int out_size, void* d_ws, size_t ws_size,
                              hipStream_t stream) {
  const float* x    = (const float*)d_in[0];
  const float* cosb = (const float*)d_in[1];
  const float* sinb = (const float*)d_in[2];
  const float* Wq   = (const float*)d_in[3];
  const float* Wk   = (const float*)d_in[4];
  const float* Wv   = (const float*)d_in[5];
  const float* Wo   = (const float*)d_in[6];
  const float* lq1  = (const float*)d_in[7];
  const float* lk1  = (const float*)d_in[8];
  const float* lq2  = (const float*)d_in[9];
  const float* lk2  = (const float*)d_in[10];
  const float* g    = (const float*)d_in[11];
  float* out = (float*)d_out;

  char* ws = (char*)d_ws;
  size_t off = 0;
  auto alloc = [&](size_t bytes) -> void* {
    void* p = ws + off;
    off += (bytes + 255) & ~(size_t)255;
    return p;
  };
  u16* xb   = (u16*)alloc((size_t)M_ROWS * Ez * 2);
  u16* Wqb  = (u16*)alloc((size_t)Ez * Ez * 2);
  u16* Wkb  = (u16*)alloc((size_t)Ez * Ez * 2);
  u16* Wvb  = (u16*)alloc((size_t)Ez * Ez * 2);
  u16* Wob  = (u16*)alloc((size_t)Ez * Ez * 2);
  float* qf = (float*)alloc((size_t)M_ROWS * Ez * 4);
  float* kf = (float*)alloc((size_t)M_ROWS * Ez * 4);
  float* vf = (float*)alloc((size_t)M_ROWS * Ez * 4);
  u16* Qb   = (u16*)alloc((size_t)Bz * 2 * Hz * Tz * Dz * 2);
  u16* Kb   = (u16*)alloc((size_t)Bz * 2 * Hz * Tz * Dz * 2);
  u16* Vt   = (u16*)alloc((size_t)Bz * Hz * 128 * Tz * 2);
  u16* Ab   = (u16*)alloc((size_t)M_ROWS * Ez * 2);

  const int n4x = M_ROWS * Ez / 4;
  cast_bf16_kernel<<<dim3(n4x / 256), 256, 0, stream>>>(x, xb, n4x);
  const int n4w = Ez * Ez / 4;
  cast_bf16_kernel<<<dim3(n4w / 256), 256, 0, stream>>>(Wq, Wqb, n4w);
  cast_bf16_kernel<<<dim3(n4w / 256), 256, 0, stream>>>(Wk, Wkb, n4w);
  cast_bf16_kernel<<<dim3(n4w / 256), 256, 0, stream>>>(Wv, Wvb, n4w);
  cast_bf16_kernel<<<dim3(n4w / 256), 256, 0, stream>>>(Wo, Wob, n4w);

  dim3 gg(M_ROWS / 128, Ez / 128);
  gemm_bt<<<gg, 256, 0, stream>>>(xb, Wqb, qf, M_ROWS, Ez, Ez);
  gemm_bt<<<gg, 256, 0, stream>>>(xb, Wkb, kf, M_ROWS, Ez, Ez);
  gemm_bt<<<gg, 256, 0, stream>>>(xb, Wvb, vf, M_ROWS, Ez, Ez);

  rope_pack_kernel<<<dim3(Bz * Tz * 2 * Hz / 256), 256, 0, stream>>>(qf, kf, cosb, sinb, Qb, Kb);
  v_pack_kernel<<<dim3(Bz * Hz * Tz / 256), 256, 0, stream>>>(vf, Vt);

  attn_kernel<<<dim3(8, Hz, Bz), 512, 0, stream>>>(Qb, Kb, Vt, lq1, lk1, lq2, lk2, g, Ab);

  gemm_bt<<<gg, 256, 0, stream>>>(Ab, Wob, out, M_ROWS, Ez, Ez);
}

// Round 5
// 523.087 us; speedup vs baseline: 2.2626x; 1.2242x over previous
//
#include <hip/hip_runtime.h>

#define DI __device__ __forceinline__
typedef unsigned short u16;
typedef __attribute__((ext_vector_type(8))) short short8;
typedef __attribute__((ext_vector_type(4))) float f32x4;

constexpr int Bz = 2, Tz = 2048, Ez = 2048, Hz = 16, Dz = 64;
constexpr int M_ROWS = Bz * Tz;  // 4096
constexpr float LAMBDA_INIT = 0.7836057665316245f;   // 0.8 - 0.6*exp(-3.6)
constexpr float ONE_MINUS_LI = 1.0f - LAMBDA_INIT;

DI u16 f2bf(float f) {
  unsigned u = __builtin_bit_cast(unsigned, f);
  u = (u + 0x7fffu + ((u >> 16) & 1u)) >> 16;  // RNE
  return (u16)u;
}

DI void gload_lds16(const void* g, void* l) {
  __builtin_amdgcn_global_load_lds((const __attribute__((address_space(1))) void*)g,
                                   (__attribute__((address_space(3))) void*)l, 16, 0, 0);
}

// ---------------- cast fp32 -> bf16 (vectorized) ----------------
__global__ void cast_bf16_kernel(const float* __restrict__ in, u16* __restrict__ out, int n4) {
  int i = blockIdx.x * blockDim.x + threadIdx.x;
  if (i >= n4) return;
  float4 v = reinterpret_cast<const float4*>(in)[i];
  ushort4 o;
  o.x = f2bf(v.x); o.y = f2bf(v.y); o.z = f2bf(v.z); o.w = f2bf(v.w);
  reinterpret_cast<ushort4*>(out)[i] = o;
}

// ---------------- pipelined GEMM: C[M,N] = A[M,K] * B[N,K]^T ----------------
// 128x128 tile, BK=64, 4 waves, double-buffered LDS, single barrier per K-step
// (stage of tile k+1 issued right after the barrier, hidden under compute of k).
// MODE 0: plain fp32 C out (N=2048).  MODE 1: fused QKV (N=6144) epilogue:
//   n<2048: RoPE+0.125 -> Qb bf16; n<4096: RoPE -> Kb bf16; else: V -> Vt transposed bf16.
template <int MODE>
__global__ __launch_bounds__(256, 2)
void gemm_pipe(const u16* __restrict__ A, const u16* __restrict__ Bm,
               float* __restrict__ C,
               const float* __restrict__ cosb, const float* __restrict__ sinb,
               u16* __restrict__ Qb, u16* __restrict__ Kb, u16* __restrict__ Vt) {
  constexpr int K = 2048;
  constexpr int NT = (MODE == 1) ? 48 : 16;  // N/128
  __shared__ u16 As[2][128 * 64];
  __shared__ u16 Bs[2][128 * 64];
  const int tid = threadIdx.x;
  const int lane = tid & 63;
  const int lq = lane & 15, lg = lane >> 4;
  const int w = tid >> 6;
  const int wm = (w >> 1) * 64, wn = (w & 1) * 64;
  // XCD-chunked bijective swizzle: xcd cc gets nt band [cc*NT/8, ...)
  const int p = blockIdx.x;
  const int cc = p & 7, idx = p >> 3;
  const int mt = idx & 31;
  const int nt = cc * (NT / 8) + (idx >> 5);
  const int m0 = mt * 128, n0 = nt * 128;

  f32x4 acc[4][4] = {};
  const u16* Ag = A + (size_t)(m0 + (tid >> 3)) * K + (tid & 7) * 8;
  const u16* Bg = Bm + (size_t)(n0 + (tid >> 3)) * K + (tid & 7) * 8;

  auto STAGE = [&](int bf, int kt) {
#pragma unroll
    for (int ch = 0; ch < 4; ++ch) {
      gload_lds16(Ag + (size_t)ch * 32 * K + kt * 64, &As[bf][(ch * 256 + tid) * 8]);
      gload_lds16(Bg + (size_t)ch * 32 * K + kt * 64, &Bs[bf][(ch * 256 + tid) * 8]);
    }
  };

  STAGE(0, 0);
  int buf = 0;
  for (int kt = 0; kt < K / 64; ++kt) {
    __syncthreads();  // drains stage(buf); all waves past reads of buf^1
    if (kt + 1 < K / 64) STAGE(buf ^ 1, kt + 1);  // in flight during compute
#pragma unroll
    for (int ks = 0; ks < 2; ++ks) {
      short8 af[4], bfr[4];
#pragma unroll
      for (int i = 0; i < 4; ++i)
        af[i] = *reinterpret_cast<const short8*>(&As[buf][(wm + i * 16 + lq) * 64 + ks * 32 + lg * 8]);
#pragma unroll
      for (int j = 0; j < 4; ++j)
        bfr[j] = *reinterpret_cast<const short8*>(&Bs[buf][(wn + j * 16 + lq) * 64 + ks * 32 + lg * 8]);
#pragma unroll
      for (int i = 0; i < 4; ++i)
#pragma unroll
        for (int j = 0; j < 4; ++j)
          acc[i][j] = __builtin_amdgcn_mfma_f32_16x16x32_bf16(af[i], bfr[j], acc[i][j], 0, 0, 0);
    }
    buf ^= 1;
  }

  if (MODE == 0) {
#pragma unroll
    for (int i = 0; i < 4; ++i)
#pragma unroll
      for (int j = 0; j < 4; ++j)
#pragma unroll
        for (int r = 0; r < 4; ++r)
          C[(size_t)(m0 + wm + i * 16 + lg * 4 + r) * 2048 + (n0 + wn + j * 16 + lq)] = acc[i][j][r];
  } else {
    const int region = n0 >> 11;  // 0:q 1:k 2:v  (uniform per block)
    if (region < 2) {
      u16* dst = (region == 0) ? Qb : Kb;
      const float qs = (region == 0) ? 0.125f : 1.0f;
#pragma unroll
      for (int j = 0; j < 4; ++j) {
        const int nl = (n0 & 2047) + wn + j * 16;
        const int hh = nl >> 6;             // uniform per j
        const int c2 = hh & 1, hd = hh >> 1;
        const int d = (nl & 63) + lq;
        const int ip = d >> 1;
        const bool odd = (d & 1) != 0;
#pragma unroll
        for (int i = 0; i < 4; ++i) {
#pragma unroll
          for (int r = 0; r < 4; ++r) {
            const int row = m0 + wm + i * 16 + lg * 4 + r;
            const int bb = row >> 11, t = row & 2047;
            const float cs = cosb[t * 32 + ip];
            const float sn = sinb[t * 32 + ip];
            const float val = acc[i][j][r];
            const float px = __shfl_xor(val, 1);
            const float o = (odd ? (sn * px + cs * val) : (cs * val - sn * px)) * qs;
            dst[((((size_t)bb * 2 + c2) * Hz + hd) * Tz + t) * 64 + d] = f2bf(o);
          }
        }
      }
    } else {
      // V: write transposed bf16 [b][h][n'][t]
#pragma unroll
      for (int j = 0; j < 4; ++j) {
        const int nv = (n0 - 4096) + wn + j * 16 + lq;
        const int hv = nv >> 7, npr = nv & 127;
#pragma unroll
        for (int i = 0; i < 4; ++i) {
          const int row0 = m0 + wm + i * 16 + lg * 4;
          const int bb = row0 >> 11, t0 = row0 & 2047;
          ushort4 o;
          o.x = f2bf(acc[i][j][0]);
          o.y = f2bf(acc[i][j][1]);
          o.z = f2bf(acc[i][j][2]);
          o.w = f2bf(acc[i][j][3]);
          *reinterpret_cast<ushort4*>(Vt + (((size_t)bb * Hz + hv) * 128 + npr) * (size_t)Tz + t0) = o;
        }
      }
    }
  }
}

// ---------------- differential flash attention + RMS-norm epilogue ----------------
// 4 waves x 16 q-rows = 64-row q-tile; KVBLK=64; 80KB LDS -> 2 blocks/CU.
// 1-D grid 512, XCD-grouped so all 16 q-tiles of one (b,h) share an XCD L2.
// Paired q-tiles (qt, 31-qt): 33 KV-steps per block, perfectly balanced.
__global__ __launch_bounds__(256, 2)
void attn_kernel(const u16* __restrict__ Qb, const u16* __restrict__ Kb,
                 const u16* __restrict__ Vt,
                 const float* __restrict__ lq1, const float* __restrict__ lk1,
                 const float* __restrict__ lq2, const float* __restrict__ lk2,
                 const float* __restrict__ g, u16* __restrict__ Ao) {
  __shared__ __align__(16) u16 Ks[2][2][64 * 64];    // 32 KB
  __shared__ __align__(16) u16 Vs[2][128 * 64];      // 32 KB
  __shared__ __align__(16) u16 Plds[4][2][16 * 64];  // 16 KB

  const int tid = threadIdx.x;
  const int l = tid & 63;
  const int lq = l & 15, lg = l >> 4;
  const int w = tid >> 6;
  // XCD-grouping decode: physical p -> logical L with 64-block chunks per XCD
  const int p = blockIdx.x;
  const int L = (p & 7) * 64 + (p >> 3);
  const int pair = L & 15;
  const int h = (L >> 4) & 15;
  const int b = L >> 8;

  float v1 = lq1[l] * lk1[l], v2 = lq2[l] * lk2[l];
#pragma unroll
  for (int off = 1; off < 64; off <<= 1) {
    v1 += __shfl_xor(v1, off);
    v2 += __shfl_xor(v2, off);
  }
  const float lambda_full = __expf(v1) - __expf(v2) + LAMBDA_INIT;

  const u16* Qp[2];
  const u16* Kp[2];
#pragma unroll
  for (int c = 0; c < 2; ++c) {
    Qp[c] = Qb + ((((size_t)b * 2 + c) * Hz + h) * Tz) * 64;
    Kp[c] = Kb + ((((size_t)b * 2 + c) * Hz + h) * Tz) * 64;
  }
  const u16* Vp = Vt + (((size_t)b * Hz + h) * 128) * (size_t)Tz;

  float gv[8];
#pragma unroll
  for (int jn = 0; jn < 8; ++jn) gv[jn] = g[jn * 16 + lq];

  for (int seg = 0; seg < 2; ++seg) {
    const int qt = seg ? (31 - pair) : pair;
    const int q0 = qt << 6;
    const int q0w = q0 + w * 16;
    const int ktmax = qt;

    short8 qfr[2][2];
#pragma unroll
    for (int c = 0; c < 2; ++c)
#pragma unroll
      for (int ks = 0; ks < 2; ++ks)
        qfr[c][ks] = *reinterpret_cast<const short8*>(
            &Qp[c][(size_t)(q0w + lq) * 64 + ks * 32 + lg * 8]);

    f32x4 O[2][8] = {};
    float mst[2][4], lp[2][4];
#pragma unroll
    for (int c = 0; c < 2; ++c)
#pragma unroll
      for (int r = 0; r < 4; ++r) { mst[c][r] = -3.0e38f; lp[c][r] = 0.f; }

    auto STAGE = [&](int bf, int kt) {
      const int kv0 = kt << 6;
#pragma unroll
      for (int c = 0; c < 2; ++c)
#pragma unroll
        for (int pp = 0; pp < 2; ++pp) {
          const int ii = pp * 256 + tid;
          const int kr = ii >> 3;
          const int kc = ((ii & 7) ^ (kr & 7)) << 3;
          gload_lds16(Kp[c] + (size_t)(kv0 + kr) * 64 + kc, &Ks[bf][c][ii * 8]);
        }
#pragma unroll
      for (int pp = 0; pp < 4; ++pp) {
        const int ii = pp * 256 + tid;
        const int vr = ii >> 3;
        const int vc = ((ii & 7) ^ (vr & 7)) << 3;
        gload_lds16(Vp + (size_t)vr * Tz + kv0 + vc, &Vs[bf][ii * 8]);
      }
    };

    STAGE(0, 0);
    int buf = 0;
    for (int kt = 0; kt <= ktmax; ++kt) {
      __syncthreads();  // stage(buf) complete; all waves past reads of buf^1
      if (kt < ktmax) STAGE(buf ^ 1, kt + 1);
      const int kv0 = kt << 6;
      const bool notfull = (kv0 + 63) > q0w;
#pragma unroll
      for (int c = 0; c < 2; ++c) {
        f32x4 s[4];
        __builtin_amdgcn_s_setprio(1);
#pragma unroll
        for (int t2 = 0; t2 < 4; ++t2) {
          f32x4 a = {0.f, 0.f, 0.f, 0.f};
#pragma unroll
          for (int ks = 0; ks < 2; ++ks) {
            const int row = t2 * 16 + lq;
            const short8 kfr = *reinterpret_cast<const short8*>(
                &Ks[buf][c][row * 64 + ((((ks << 2) + lg) ^ (row & 7)) << 3)]);
            a = __builtin_amdgcn_mfma_f32_16x16x32_bf16(qfr[c][ks], kfr, a, 0, 0, 0);
          }
          s[t2] = a;
        }
        __builtin_amdgcn_s_setprio(0);
        if (notfull) {
#pragma unroll
          for (int t2 = 0; t2 < 4; ++t2)
#pragma unroll
            for (int r = 0; r < 4; ++r)
              if (kv0 + t2 * 16 + lq > q0w + lg * 4 + r) s[t2][r] = -3.0e38f;
        }
        // row maxes via 16-lane shfl chains
        float mx[4];
#pragma unroll
        for (int r = 0; r < 4; ++r) {
          float m2 = fmaxf(fmaxf(s[0][r], s[1][r]), fmaxf(s[2][r], s[3][r]));
          m2 = fmaxf(m2, __shfl_xor(m2, 1));
          m2 = fmaxf(m2, __shfl_xor(m2, 2));
          m2 = fmaxf(m2, __shfl_xor(m2, 4));
          m2 = fmaxf(m2, __shfl_xor(m2, 8));
          mx[r] = m2;
        }
        // defer-max (T13): skip rescale when max growth <= 8
        const float dm = fmaxf(fmaxf(mx[0] - mst[c][0], mx[1] - mst[c][1]),
                               fmaxf(mx[2] - mst[c][2], mx[3] - mst[c][3]));
        if (!__all(dm <= 8.0f)) {
          float alr[4];
#pragma unroll
          for (int r = 0; r < 4; ++r) {
            const float mnew = fmaxf(mst[c][r], mx[r]);
            const float alpha = __expf(mst[c][r] - mnew);
            lp[c][r] *= alpha;
            mst[c][r] = mnew;
            alr[r] = alpha;
          }
#pragma unroll
          for (int jn = 0; jn < 8; ++jn)
#pragma unroll
            for (int r = 0; r < 4; ++r)
              O[c][jn][r] *= alr[r];
        }
        // exp + per-lane partial row-sum (cross-lane sum deferred to epilogue)
#pragma unroll
        for (int r = 0; r < 4; ++r) {
          float psum = 0.f;
#pragma unroll
          for (int t2 = 0; t2 < 4; ++t2) {
            const float pe = __expf(s[t2][r] - mst[c][r]);
            s[t2][r] = pe;
            psum += pe;
          }
          lp[c][r] += psum;
        }
        // P (C-layout) -> LDS -> A-fragment layout (swizzled)
        u16* pl = &Plds[w][c][0];
#pragma unroll
        for (int t2 = 0; t2 < 4; ++t2)
#pragma unroll
          for (int r = 0; r < 4; ++r) {
            const int prow = lg * 4 + r, pcol = t2 * 16 + lq;
            pl[prow * 64 + (((pcol >> 3) ^ (prow & 7)) << 3) + (pcol & 7)] = f2bf(s[t2][r]);
          }
      }
      asm volatile("s_waitcnt lgkmcnt(0)" ::: "memory");
      __builtin_amdgcn_sched_barrier(0);
      short8 pf[2][2];
#pragma unroll
      for (int c = 0; c < 2; ++c)
#pragma unroll
        for (int kseg = 0; kseg < 2; ++kseg)
          pf[c][kseg] = *reinterpret_cast<const short8*>(
              &Plds[w][c][lq * 64 + ((((kseg << 2) + lg) ^ (lq & 7)) << 3)]);
      __builtin_amdgcn_s_setprio(1);
#pragma unroll
      for (int jn = 0; jn < 8; ++jn)
#pragma unroll
        for (int kseg = 0; kseg < 2; ++kseg) {
          const int vr = jn * 16 + lq;
          const short8 vfr = *reinterpret_cast<const short8*>(
              &Vs[buf][vr * 64 + ((((kseg << 2) + lg) ^ (vr & 7)) << 3)]);
          O[0][jn] = __builtin_amdgcn_mfma_f32_16x16x32_bf16(pf[0][kseg], vfr, O[0][jn], 0, 0, 0);
          O[1][jn] = __builtin_amdgcn_mfma_f32_16x16x32_bf16(pf[1][kseg], vfr, O[1][jn], 0, 0, 0);
        }
      __builtin_amdgcn_s_setprio(0);
      buf ^= 1;
    }

    // final cross-lane row-sums
    float lst[2][4];
#pragma unroll
    for (int c = 0; c < 2; ++c)
#pragma unroll
      for (int r = 0; r < 4; ++r) {
        float ls = lp[c][r];
        ls += __shfl_xor(ls, 1);
        ls += __shfl_xor(ls, 2);
        ls += __shfl_xor(ls, 4);
        ls += __shfl_xor(ls, 8);
        lst[c][r] = ls;
      }

    // epilogue: combine, RMS-norm over 128, * g * (1 - lambda_init), write bf16
#pragma unroll
    for (int r = 0; r < 4; ++r) {
      const float inv1 = 1.f / lst[0][r];
      const float inv2 = 1.f / lst[1][r];
      float av[8];
      float ss = 0.f;
#pragma unroll
      for (int jn = 0; jn < 8; ++jn) {
        const float a2 = O[0][jn][r] * inv1 - lambda_full * (O[1][jn][r] * inv2);
        av[jn] = a2;
        ss += a2 * a2;
      }
      ss += __shfl_xor(ss, 1);
      ss += __shfl_xor(ss, 2);
      ss += __shfl_xor(ss, 4);
      ss += __shfl_xor(ss, 8);
      const float sc = rsqrtf(ss * (1.f / 128.f) + 1e-5f) * ONE_MINUS_LI;
      const int row = q0w + lg * 4 + r;
      u16* orow = Ao + ((size_t)b * Tz + row) * 2048 + h * 128;
#pragma unroll
      for (int jn = 0; jn < 8; ++jn)
        orow[jn * 16 + lq] = f2bf(av[jn] * sc * gv[jn]);
    }
    __syncthreads();  // protect LDS before seg 1 re-stage
  }
}

extern "C" void kernel_launch(void* const* d_in, const int* in_sizes, int n_in,
                              void* d_out, int out_size, void* d_ws, size_t ws_size,
                              hipStream_t stream) {
  const float* x    = (const float*)d_in[0];
  const float* cosb = (const float*)d_in[1];
  const float* sinb = (const float*)d_in[2];
  const float* Wq   = (const float*)d_in[3];
  const float* Wk   = (const float*)d_in[4];
  const float* Wv   = (const float*)d_in[5];
  const float* Wo   = (const float*)d_in[6];
  const float* lq1  = (const float*)d_in[7];
  const float* lk1  = (const float*)d_in[8];
  const float* lq2  = (const float*)d_in[9];
  const float* lk2  = (const float*)d_in[10];
  const float* g    = (const float*)d_in[11];
  float* out = (float*)d_out;

  char* ws = (char*)d_ws;
  size_t off = 0;
  auto alloc = [&](size_t bytes) -> void* {
    void* p = ws + off;
    off += (bytes + 255) & ~(size_t)255;
    return p;
  };
  u16* xb    = (u16*)alloc((size_t)M_ROWS * Ez * 2);
  u16* Wqkvb = (u16*)alloc((size_t)3 * Ez * Ez * 2);
  u16* Wob   = (u16*)alloc((size_t)Ez * Ez * 2);
  u16* Qb    = (u16*)alloc((size_t)Bz * 2 * Hz * Tz * Dz * 2);
  u16* Kb    = (u16*)alloc((size_t)Bz * 2 * Hz * Tz * Dz * 2);
  u16* Vt    = (u16*)alloc((size_t)Bz * Hz * 128 * Tz * 2);
  u16* Ab    = (u16*)alloc((size_t)M_ROWS * Ez * 2);

  const int n4x = M_ROWS * Ez / 4;
  cast_bf16_kernel<<<dim3(n4x / 256), 256, 0, stream>>>(x, xb, n4x);
  const int n4w = Ez * Ez / 4;
  cast_bf16_kernel<<<dim3(n4w / 256), 256, 0, stream>>>(Wq, Wqkvb, n4w);
  cast_bf16_kernel<<<dim3(n4w / 256), 256, 0, stream>>>(Wk, Wqkvb + (size_t)Ez * Ez, n4w);
  cast_bf16_kernel<<<dim3(n4w / 256), 256, 0, stream>>>(Wv, Wqkvb + (size_t)2 * Ez * Ez, n4w);
  cast_bf16_kernel<<<dim3(n4w / 256), 256, 0, stream>>>(Wo, Wob, n4w);

  // fused QKV GEMM + RoPE/V-transpose epilogue (M=4096, N=6144, K=2048)
  gemm_pipe<1><<<dim3(1536), 256, 0, stream>>>(xb, Wqkvb, nullptr, cosb, sinb, Qb, Kb, Vt);

  attn_kernel<<<dim3(512), 256, 0, stream>>>(Qb, Kb, Vt, lq1, lk1, lq2, lk2, g, Ab);

  // output GEMM (M=4096, N=2048, K=2048), fp32 out
  gemm_pipe<0><<<dim3(512), 256, 0, stream>>>(Ab, Wob, out, nullptr, nullptr, nullptr, nullptr, nullptr);
}

// Round 6
// 446.237 us; speedup vs baseline: 2.6523x; 1.1722x over previous
//
#include <hip/hip_runtime.h>

#define DI __device__ __forceinline__
typedef unsigned short u16;
typedef __attribute__((ext_vector_type(8))) short short8;
typedef __attribute__((ext_vector_type(4))) float f32x4;

constexpr int Bz = 2, Tz = 2048, Ez = 2048, Hz = 16, Dz = 64;
constexpr int M_ROWS = Bz * Tz;  // 4096
constexpr float LAMBDA_INIT = 0.7836057665316245f;   // 0.8 - 0.6*exp(-3.6)
constexpr float ONE_MINUS_LI = 1.0f - LAMBDA_INIT;

DI u16 f2bf(float f) {
  unsigned u = __builtin_bit_cast(unsigned, f);
  u = (u + 0x7fffu + ((u >> 16) & 1u)) >> 16;  // RNE
  return (u16)u;
}

DI void gload_lds16(const void* g, void* l) {
  __builtin_amdgcn_global_load_lds((const __attribute__((address_space(1))) void*)g,
                                   (__attribute__((address_space(3))) void*)l, 16, 0, 0);
}

// ---------------- cast fp32 -> bf16 (vectorized) ----------------
__global__ void cast_bf16_kernel(const float* __restrict__ in, u16* __restrict__ out, int n4) {
  int i = blockIdx.x * blockDim.x + threadIdx.x;
  if (i >= n4) return;
  float4 v = reinterpret_cast<const float4*>(in)[i];
  ushort4 o;
  o.x = f2bf(v.x); o.y = f2bf(v.y); o.z = f2bf(v.z); o.w = f2bf(v.w);
  reinterpret_cast<ushort4*>(out)[i] = o;
}

// ---------------- GEMM (m97 structure): C[M,N] = A[M,K] * B[N,K]^T ----------------
// 128x128 tile, BK=64, 4 waves, SINGLE 32KB LDS buffer, 2 barriers per K-step.
// Implicit wave-level overlap at 4 blocks/CU beats explicit dbuf at 2 blocks/CU (m132).
// MODE 0: plain fp32 C out (N=2048).  MODE 1: fused QKV (N=6144) epilogue:
//   n<2048: RoPE+0.125 -> Qb bf16; n<4096: RoPE -> Kb bf16; else: V -> Vt transposed bf16.
template <int MODE>
__global__ __launch_bounds__(256, 2)
void gemm_pipe(const u16* __restrict__ A, const u16* __restrict__ Bm,
               float* __restrict__ C,
               const float* __restrict__ cosb, const float* __restrict__ sinb,
               u16* __restrict__ Qb, u16* __restrict__ Kb, u16* __restrict__ Vt) {
  constexpr int K = 2048;
  constexpr int NT = (MODE == 1) ? 48 : 16;  // N/128
  __shared__ u16 As[128 * 64];
  __shared__ u16 Bs[128 * 64];
  const int tid = threadIdx.x;
  const int lane = tid & 63;
  const int lq = lane & 15, lg = lane >> 4;
  const int w = tid >> 6;
  const int wm = (w >> 1) * 64, wn = (w & 1) * 64;
  // XCD-chunked bijective swizzle: xcd cc gets nt band [cc*NT/8, ...)
  const int p = blockIdx.x;
  const int cc = p & 7, idx = p >> 3;
  const int mt = idx & 31;
  const int nt = cc * (NT / 8) + (idx >> 5);
  const int m0 = mt * 128, n0 = nt * 128;

  f32x4 acc[4][4] = {};
  const u16* Ag = A + (size_t)(m0 + (tid >> 3)) * K + (tid & 7) * 8;
  const u16* Bg = Bm + (size_t)(n0 + (tid >> 3)) * K + (tid & 7) * 8;

  for (int kt = 0; kt < K; kt += 64) {
    __syncthreads();  // readers done with As/Bs
#pragma unroll
    for (int ch = 0; ch < 4; ++ch) {
      gload_lds16(Ag + (size_t)ch * 32 * K + kt, &As[(ch * 256 + tid) * 8]);
      gload_lds16(Bg + (size_t)ch * 32 * K + kt, &Bs[(ch * 256 + tid) * 8]);
    }
    __syncthreads();  // stage visible (compiler drains vmcnt before barrier)
#pragma unroll
    for (int ks = 0; ks < 2; ++ks) {
      short8 af[4], bfr[4];
#pragma unroll
      for (int i = 0; i < 4; ++i)
        af[i] = *reinterpret_cast<const short8*>(&As[(wm + i * 16 + lq) * 64 + ks * 32 + lg * 8]);
#pragma unroll
      for (int j = 0; j < 4; ++j)
        bfr[j] = *reinterpret_cast<const short8*>(&Bs[(wn + j * 16 + lq) * 64 + ks * 32 + lg * 8]);
#pragma unroll
      for (int i = 0; i < 4; ++i)
#pragma unroll
        for (int j = 0; j < 4; ++j)
          acc[i][j] = __builtin_amdgcn_mfma_f32_16x16x32_bf16(af[i], bfr[j], acc[i][j], 0, 0, 0);
    }
  }

  if (MODE == 0) {
#pragma unroll
    for (int i = 0; i < 4; ++i)
#pragma unroll
      for (int j = 0; j < 4; ++j)
#pragma unroll
        for (int r = 0; r < 4; ++r)
          C[(size_t)(m0 + wm + i * 16 + lg * 4 + r) * 2048 + (n0 + wn + j * 16 + lq)] = acc[i][j][r];
  } else {
    const int region = n0 >> 11;  // 0:q 1:k 2:v  (uniform per block)
    if (region < 2) {
      u16* dst = (region == 0) ? Qb : Kb;
      const float qs = (region == 0) ? 0.125f : 1.0f;
#pragma unroll
      for (int j = 0; j < 4; ++j) {
        const int nl = (n0 & 2047) + wn + j * 16;
        const int hh = nl >> 6;             // uniform per j
        const int c2 = hh & 1, hd = hh >> 1;
        const int d = (nl & 63) + lq;
        const int ip = d >> 1;
        const bool odd = (d & 1) != 0;
#pragma unroll
        for (int i = 0; i < 4; ++i) {
#pragma unroll
          for (int r = 0; r < 4; ++r) {
            const int row = m0 + wm + i * 16 + lg * 4 + r;
            const int bb = row >> 11, t = row & 2047;
            const float cs = cosb[t * 32 + ip];
            const float sn = sinb[t * 32 + ip];
            const float val = acc[i][j][r];
            const float px = __shfl_xor(val, 1);
            const float o = (odd ? (sn * px + cs * val) : (cs * val - sn * px)) * qs;
            dst[((((size_t)bb * 2 + c2) * Hz + hd) * Tz + t) * 64 + d] = f2bf(o);
          }
        }
      }
    } else {
      // V: write transposed bf16 [b][h][n'][t]
#pragma unroll
      for (int j = 0; j < 4; ++j) {
        const int nv = (n0 - 4096) + wn + j * 16 + lq;
        const int hv = nv >> 7, npr = nv & 127;
#pragma unroll
        for (int i = 0; i < 4; ++i) {
          const int row0 = m0 + wm + i * 16 + lg * 4;
          const int bb = row0 >> 11, t0 = row0 & 2047;
          ushort4 o;
          o.x = f2bf(acc[i][j][0]);
          o.y = f2bf(acc[i][j][1]);
          o.z = f2bf(acc[i][j][2]);
          o.w = f2bf(acc[i][j][3]);
          *reinterpret_cast<ushort4*>(Vt + (((size_t)bb * Hz + hv) * 128 + npr) * (size_t)Tz + t0) = o;
        }
      }
    }
  }
}

// ---------------- differential flash attention + RMS-norm epilogue ----------------
// 4 waves x 16 q-rows = 64-row q-tile; KVBLK=64; 80KB LDS -> 2 blocks/CU.
// 1-D grid 512, XCD-grouped so all 16 q-tiles of one (b,h) share an XCD L2.
// Paired q-tiles (qt, 31-qt): 33 KV-steps per block, perfectly balanced.
__global__ __launch_bounds__(256, 2)
void attn_kernel(const u16* __restrict__ Qb, const u16* __restrict__ Kb,
                 const u16* __restrict__ Vt,
                 const float* __restrict__ lq1, const float* __restrict__ lk1,
                 const float* __restrict__ lq2, const float* __restrict__ lk2,
                 const float* __restrict__ g, u16* __restrict__ Ao) {
  __shared__ __align__(16) u16 Ks[2][2][64 * 64];    // 32 KB
  __shared__ __align__(16) u16 Vs[2][128 * 64];      // 32 KB
  __shared__ __align__(16) u16 Plds[4][2][16 * 64];  // 16 KB

  const int tid = threadIdx.x;
  const int l = tid & 63;
  const int lq = l & 15, lg = l >> 4;
  const int w = tid >> 6;
  // XCD-grouping decode: physical p -> logical L with 64-block chunks per XCD
  const int p = blockIdx.x;
  const int L = (p & 7) * 64 + (p >> 3);
  const int pair = L & 15;
  const int h = (L >> 4) & 15;
  const int b = L >> 8;

  float v1 = lq1[l] * lk1[l], v2 = lq2[l] * lk2[l];
#pragma unroll
  for (int off = 1; off < 64; off <<= 1) {
    v1 += __shfl_xor(v1, off);
    v2 += __shfl_xor(v2, off);
  }
  const float lambda_full = __expf(v1) - __expf(v2) + LAMBDA_INIT;

  const u16* Qp[2];
  const u16* Kp[2];
#pragma unroll
  for (int c = 0; c < 2; ++c) {
    Qp[c] = Qb + ((((size_t)b * 2 + c) * Hz + h) * Tz) * 64;
    Kp[c] = Kb + ((((size_t)b * 2 + c) * Hz + h) * Tz) * 64;
  }
  const u16* Vp = Vt + (((size_t)b * Hz + h) * 128) * (size_t)Tz;

  float gv[8];
#pragma unroll
  for (int jn = 0; jn < 8; ++jn) gv[jn] = g[jn * 16 + lq];

  for (int seg = 0; seg < 2; ++seg) {
    const int qt = seg ? (31 - pair) : pair;
    const int q0 = qt << 6;
    const int q0w = q0 + w * 16;
    const int ktmax = qt;

    short8 qfr[2][2];
#pragma unroll
    for (int c = 0; c < 2; ++c)
#pragma unroll
      for (int ks = 0; ks < 2; ++ks)
        qfr[c][ks] = *reinterpret_cast<const short8*>(
            &Qp[c][(size_t)(q0w + lq) * 64 + ks * 32 + lg * 8]);

    f32x4 O[2][8] = {};
    float mst[2][4], lp[2][4];
#pragma unroll
    for (int c = 0; c < 2; ++c)
#pragma unroll
      for (int r = 0; r < 4; ++r) { mst[c][r] = -3.0e38f; lp[c][r] = 0.f; }

    auto STAGE = [&](int bf, int kt) {
      const int kv0 = kt << 6;
#pragma unroll
      for (int c = 0; c < 2; ++c)
#pragma unroll
        for (int pp = 0; pp < 2; ++pp) {
          const int ii = pp * 256 + tid;
          const int kr = ii >> 3;
          const int kc = ((ii & 7) ^ (kr & 7)) << 3;
          gload_lds16(Kp[c] + (size_t)(kv0 + kr) * 64 + kc, &Ks[bf][c][ii * 8]);
        }
#pragma unroll
      for (int pp = 0; pp < 4; ++pp) {
        const int ii = pp * 256 + tid;
        const int vr = ii >> 3;
        const int vc = ((ii & 7) ^ (vr & 7)) << 3;
        gload_lds16(Vp + (size_t)vr * Tz + kv0 + vc, &Vs[bf][ii * 8]);
      }
    };

    STAGE(0, 0);
    int buf = 0;
    for (int kt = 0; kt <= ktmax; ++kt) {
      __syncthreads();  // stage(buf) complete; all waves past reads of buf^1
      if (kt < ktmax) STAGE(buf ^ 1, kt + 1);
      const int kv0 = kt << 6;
      const bool notfull = (kv0 + 63) > q0w;
#pragma unroll
      for (int c = 0; c < 2; ++c) {
        f32x4 s[4];
        __builtin_amdgcn_s_setprio(1);
#pragma unroll
        for (int t2 = 0; t2 < 4; ++t2) {
          f32x4 a = {0.f, 0.f, 0.f, 0.f};
#pragma unroll
          for (int ks = 0; ks < 2; ++ks) {
            const int row = t2 * 16 + lq;
            const short8 kfr = *reinterpret_cast<const short8*>(
                &Ks[buf][c][row * 64 + ((((ks << 2) + lg) ^ (row & 7)) << 3)]);
            a = __builtin_amdgcn_mfma_f32_16x16x32_bf16(qfr[c][ks], kfr, a, 0, 0, 0);
          }
          s[t2] = a;
        }
        __builtin_amdgcn_s_setprio(0);
        if (notfull) {
#pragma unroll
          for (int t2 = 0; t2 < 4; ++t2)
#pragma unroll
            for (int r = 0; r < 4; ++r)
              if (kv0 + t2 * 16 + lq > q0w + lg * 4 + r) s[t2][r] = -3.0e38f;
        }
        // row maxes via 16-lane shfl chains
        float mx[4];
#pragma unroll
        for (int r = 0; r < 4; ++r) {
          float m2 = fmaxf(fmaxf(s[0][r], s[1][r]), fmaxf(s[2][r], s[3][r]));
          m2 = fmaxf(m2, __shfl_xor(m2, 1));
          m2 = fmaxf(m2, __shfl_xor(m2, 2));
          m2 = fmaxf(m2, __shfl_xor(m2, 4));
          m2 = fmaxf(m2, __shfl_xor(m2, 8));
          mx[r] = m2;
        }
        // defer-max (T13): skip rescale when max growth <= 8
        const float dm = fmaxf(fmaxf(mx[0] - mst[c][0], mx[1] - mst[c][1]),
                               fmaxf(mx[2] - mst[c][2], mx[3] - mst[c][3]));
        if (!__all(dm <= 8.0f)) {
          float alr[4];
#pragma unroll
          for (int r = 0; r < 4; ++r) {
            const float mnew = fmaxf(mst[c][r], mx[r]);
            const float alpha = __expf(mst[c][r] - mnew);
            lp[c][r] *= alpha;
            mst[c][r] = mnew;
            alr[r] = alpha;
          }
#pragma unroll
          for (int jn = 0; jn < 8; ++jn)
#pragma unroll
            for (int r = 0; r < 4; ++r)
              O[c][jn][r] *= alr[r];
        }
        // exp + per-lane partial row-sum (cross-lane sum deferred to epilogue)
#pragma unroll
        for (int r = 0; r < 4; ++r) {
          float psum = 0.f;
#pragma unroll
          for (int t2 = 0; t2 < 4; ++t2) {
            const float pe = __expf(s[t2][r] - mst[c][r]);
            s[t2][r] = pe;
            psum += pe;
          }
          lp[c][r] += psum;
        }
        // P (C-layout) -> LDS -> A-fragment layout (swizzled)
        u16* pl = &Plds[w][c][0];
#pragma unroll
        for (int t2 = 0; t2 < 4; ++t2)
#pragma unroll
          for (int r = 0; r < 4; ++r) {
            const int prow = lg * 4 + r, pcol = t2 * 16 + lq;
            pl[prow * 64 + (((pcol >> 3) ^ (prow & 7)) << 3) + (pcol & 7)] = f2bf(s[t2][r]);
          }
      }
      asm volatile("s_waitcnt lgkmcnt(0)" ::: "memory");
      __builtin_amdgcn_sched_barrier(0);
      short8 pf[2][2];
#pragma unroll
      for (int c = 0; c < 2; ++c)
#pragma unroll
        for (int kseg = 0; kseg < 2; ++kseg)
          pf[c][kseg] = *reinterpret_cast<const short8*>(
              &Plds[w][c][lq * 64 + ((((kseg << 2) + lg) ^ (lq & 7)) << 3)]);
      __builtin_amdgcn_s_setprio(1);
#pragma unroll
      for (int jn = 0; jn < 8; ++jn)
#pragma unroll
        for (int kseg = 0; kseg < 2; ++kseg) {
          const int vr = jn * 16 + lq;
          const short8 vfr = *reinterpret_cast<const short8*>(
              &Vs[buf][vr * 64 + ((((kseg << 2) + lg) ^ (vr & 7)) << 3)]);
          O[0][jn] = __builtin_amdgcn_mfma_f32_16x16x32_bf16(pf[0][kseg], vfr, O[0][jn], 0, 0, 0);
          O[1][jn] = __builtin_amdgcn_mfma_f32_16x16x32_bf16(pf[1][kseg], vfr, O[1][jn], 0, 0, 0);
        }
      __builtin_amdgcn_s_setprio(0);
      buf ^= 1;
    }

    // final cross-lane row-sums
    float lst[2][4];
#pragma unroll
    for (int c = 0; c < 2; ++c)
#pragma unroll
      for (int r = 0; r < 4; ++r) {
        float ls = lp[c][r];
        ls += __shfl_xor(ls, 1);
        ls += __shfl_xor(ls, 2);
        ls += __shfl_xor(ls, 4);
        ls += __shfl_xor(ls, 8);
        lst[c][r] = ls;
      }

    // epilogue: combine, RMS-norm over 128, * g * (1 - lambda_init), write bf16
#pragma unroll
    for (int r = 0; r < 4; ++r) {
      const float inv1 = 1.f / lst[0][r];
      const float inv2 = 1.f / lst[1][r];
      float av[8];
      float ss = 0.f;
#pragma unroll
      for (int jn = 0; jn < 8; ++jn) {
        const float a2 = O[0][jn][r] * inv1 - lambda_full * (O[1][jn][r] * inv2);
        av[jn] = a2;
        ss += a2 * a2;
      }
      ss += __shfl_xor(ss, 1);
      ss += __shfl_xor(ss, 2);
      ss += __shfl_xor(ss, 4);
      ss += __shfl_xor(ss, 8);
      const float sc = rsqrtf(ss * (1.f / 128.f) + 1e-5f) * ONE_MINUS_LI;
      const int row = q0w + lg * 4 + r;
      u16* orow = Ao + ((size_t)b * Tz + row) * 2048 + h * 128;
#pragma unroll
      for (int jn = 0; jn < 8; ++jn)
        orow[jn * 16 + lq] = f2bf(av[jn] * sc * gv[jn]);
    }
    __syncthreads();  // protect LDS before seg 1 re-stage
  }
}

extern "C" void kernel_launch(void* const* d_in, const int* in_sizes, int n_in,
                              void* d_out, int out_size, void* d_ws, size_t ws_size,
                              hipStream_t stream) {
  const float* x    = (const float*)d_in[0];
  const float* cosb = (const float*)d_in[1];
  const float* sinb = (const float*)d_in[2];
  const float* Wq   = (const float*)d_in[3];
  const float* Wk   = (const float*)d_in[4];
  const float* Wv   = (const float*)d_in[5];
  const float* Wo   = (const float*)d_in[6];
  const float* lq1  = (const float*)d_in[7];
  const float* lk1  = (const float*)d_in[8];
  const float* lq2  = (const float*)d_in[9];
  const float* lk2  = (const float*)d_in[10];
  const float* g    = (const float*)d_in[11];
  float* out = (float*)d_out;

  char* ws = (char*)d_ws;
  size_t off = 0;
  auto alloc = [&](size_t bytes) -> void* {
    void* p = ws + off;
    off += (bytes + 255) & ~(size_t)255;
    return p;
  };
  u16* xb    = (u16*)alloc((size_t)M_ROWS * Ez * 2);
  u16* Wqkvb = (u16*)alloc((size_t)3 * Ez * Ez * 2);
  u16* Wob   = (u16*)alloc((size_t)Ez * Ez * 2);
  u16* Qb    = (u16*)alloc((size_t)Bz * 2 * Hz * Tz * Dz * 2);
  u16* Kb    = (u16*)alloc((size_t)Bz * 2 * Hz * Tz * Dz * 2);
  u16* Vt    = (u16*)alloc((size_t)Bz * Hz * 128 * Tz * 2);
  u16* Ab    = (u16*)alloc((size_t)M_ROWS * Ez * 2);

  const int n4x = M_ROWS * Ez / 4;
  cast_bf16_kernel<<<dim3(n4x / 256), 256, 0, stream>>>(x, xb, n4x);
  const int n4w = Ez * Ez / 4;
  cast_bf16_kernel<<<dim3(n4w / 256), 256, 0, stream>>>(Wq, Wqkvb, n4w);
  cast_bf16_kernel<<<dim3(n4w / 256), 256, 0, stream>>>(Wk, Wqkvb + (size_t)Ez * Ez, n4w);
  cast_bf16_kernel<<<dim3(n4w / 256), 256, 0, stream>>>(Wv, Wqkvb + (size_t)2 * Ez * Ez, n4w);
  cast_bf16_kernel<<<dim3(n4w / 256), 256, 0, stream>>>(Wo, Wob, n4w);

  // fused QKV GEMM + RoPE/V-transpose epilogue (M=4096, N=6144, K=2048)
  gemm_pipe<1><<<dim3(1536), 256, 0, stream>>>(xb, Wqkvb, nullptr, cosb, sinb, Qb, Kb, Vt);

  attn_kernel<<<dim3(512), 256, 0, stream>>>(Qb, Kb, Vt, lq1, lk1, lq2, lk2, g, Ab);

  // output GEMM (M=4096, N=2048, K=2048), fp32 out
  gemm_pipe<0><<<dim3(512), 256, 0, stream>>>(Ab, Wob, out, nullptr, nullptr, nullptr, nullptr, nullptr);
}